// Round 1
// baseline (219.238 us; speedup 1.0000x reference)
//
#include <hip/hip_runtime.h>

#define V 200000
#define R 100
#define D 128
#define K 20
#define B 128
#define N 50

// ---------------------------------------------------------------------------
// Kernel A: per-row dots with the three W_att segments (logit separability).
//   s0[v] = EE[v] . Watt[0:D]     (v < V)
//   s1[v] = EE[v] . Watt[D:2D]    (v < V)
//   s2[r] = RE[r] . Watt[2D:3D]   (r < R, rows V..V+R-1)
// One wave per row, float2/lane -> one coalesced 512B read per row.
// Pure streaming of EE at HBM/L3 bandwidth.
// ---------------------------------------------------------------------------
__global__ void k_scores(const float* __restrict__ EE,
                         const float* __restrict__ RE,
                         const float* __restrict__ Watt,
                         float* __restrict__ s0,
                         float* __restrict__ s1,
                         float* __restrict__ s2) {
  const int lane = threadIdx.x & 63;
  const int row  = blockIdx.x * 4 + (threadIdx.x >> 6);
  if (row < V) {
    const float2 w0 = ((const float2*)Watt)[lane];
    const float2 w1 = ((const float2*)(Watt + D))[lane];
    const float2 e  = ((const float2*)(EE + (size_t)row * D))[lane];
    float p0 = e.x * w0.x + e.y * w0.y;
    float p1 = e.x * w1.x + e.y * w1.y;
    #pragma unroll
    for (int off = 32; off > 0; off >>= 1) {
      p0 += __shfl_down(p0, off);
      p1 += __shfl_down(p1, off);
    }
    if (lane == 0) { s0[row] = p0; s1[row] = p1; }
  } else if (row < V + R) {
    const float2 w2 = ((const float2*)(Watt + 2 * D))[lane];
    const float2 e  = ((const float2*)(RE + (size_t)(row - V) * D))[lane];
    float p2 = e.x * w2.x + e.y * w2.y;
    #pragma unroll
    for (int off = 32; off > 0; off >>= 1) p2 += __shfl_down(p2, off);
    if (lane == 0) s2[row - V] = p2;
  }
}

// ---------------------------------------------------------------------------
// Kernel B: fused logits + softmax over the batch axis.
// One block of 128 threads (= B) per (n,k). Thread b:
//   l = relu(s0[eid] + s1[nid] + s2[rid] + b_att)
// then block-wide softmax over b. All gathers are 4B scalars from small,
// L2-resident tables (s0/s1 = 800KB each).
// ---------------------------------------------------------------------------
__global__ void k_att(const int* __restrict__ eids,
                      const int* __restrict__ adjE,
                      const int* __restrict__ adjR,
                      const float* __restrict__ s0,
                      const float* __restrict__ s1,
                      const float* __restrict__ s2,
                      const float* __restrict__ batt,
                      float* __restrict__ att) {
  __shared__ float red[4];
  const int gg = blockIdx.x;            // n*K + k
  const int n  = gg / K;
  const int k  = gg % K;
  const int b  = threadIdx.x;           // 0..127

  const int eid = eids[b * N + n];
  const int nid = adjE[eid * K + k];
  const int rid = adjR[eid * K + k];
  float l = s0[eid] + s1[nid] + s2[rid] + batt[0];
  l = l > 0.0f ? l : 0.0f;

  // softmax over the 128 threads (2 waves)
  float m = l;
  #pragma unroll
  for (int off = 32; off > 0; off >>= 1) m = fmaxf(m, __shfl_down(m, off));
  if ((b & 63) == 0) red[b >> 6] = m;
  __syncthreads();
  const float mm = fmaxf(red[0], red[1]);

  const float e = __expf(l - mm);
  float s = e;
  #pragma unroll
  for (int off = 32; off > 0; off >>= 1) s += __shfl_down(s, off);
  if ((b & 63) == 0) red[2 + (b >> 6)] = s;
  __syncthreads();
  const float ss = red[2] + red[3];

  att[gg * B + b] = e / ss;
}

// ---------------------------------------------------------------------------
// Kernel 3: neighbor_att + epilogue GEMV (unchanged from prior session).
// G=8 pairs per block, 256 threads = (d 0..127) x (h 0..1).
// ---------------------------------------------------------------------------
#define G 8
__global__ void k_out(const int* __restrict__ eids,
                      const int* __restrict__ adjE,
                      const float* __restrict__ EE,
                      const float* __restrict__ att,
                      const float* __restrict__ Wc,
                      const float* __restrict__ bc,
                      float* __restrict__ out) {
  __shared__ float agg[G][2 * D];        // 8 KB
  __shared__ float part[2][G][D];        // 8 KB
  __shared__ float s_att[G][K];
  __shared__ int   s_nid[G][K];

  const int t = threadIdx.x;             // 0 .. 255
  const int d = t & 127;
  const int h = t >> 7;
  const int base = blockIdx.x * G;

  // stage neighbor ids + attention scalars (160 threads)
  if (t < G * K) {
    const int j = t / K, k = t % K;
    const int bn = base + j;
    const int b = bn / N;
    const int n = bn % N;
    const int eid = eids[bn];
    s_nid[j][k] = adjE[eid * K + k];
    s_att[j][k] = att[(n * K + k) * B + b];
  }
  __syncthreads();

  // phase 1: gather + weighted sum; half h covers pairs j = h, h+2, ...
  #pragma unroll
  for (int jj = 0; jj < G / 2; ++jj) {
    const int j = h + jj * 2;
    const int bn = base + j;
    const int eid = eids[bn];
    const float ee = EE[(size_t)eid * D + d];
    float na = 0.0f;
    #pragma unroll
    for (int k = 0; k < K; ++k)
      na += s_att[j][k] * EE[(size_t)s_nid[j][k] * D + d];
    agg[j][d] = ee;
    agg[j][D + d] = na;
  }
  __syncthreads();

  // phase 2: partial GEMV over i in [128h, 128h+128), all G pairs
  float acc[G];
  #pragma unroll
  for (int j = 0; j < G; ++j) acc[j] = 0.0f;
  const int ibase = h * D;
  for (int c = 0; c < 32; ++c) {
    const int i = ibase + c * 4;
    const float w0 = Wc[(i + 0) * D + d];
    const float w1 = Wc[(i + 1) * D + d];
    const float w2 = Wc[(i + 2) * D + d];
    const float w3 = Wc[(i + 3) * D + d];
    #pragma unroll
    for (int j = 0; j < G; ++j) {
      const float4 a = *(const float4*)&agg[j][i];   // same-address broadcast
      acc[j] += a.x * w0 + a.y * w1 + a.z * w2 + a.w * w3;
    }
  }
  #pragma unroll
  for (int j = 0; j < G; ++j) part[h][j][d] = acc[j];
  __syncthreads();

  // combine halves + bias + relu
  const float bb = bc[d];
  #pragma unroll
  for (int jj = 0; jj < G / 2; ++jj) {
    const int j = h + jj * 2;
    const float v = part[0][j][d] + part[1][j][d] + bb;
    out[(size_t)(base + j) * D + d] = v > 0.0f ? v : 0.0f;
  }
}

// ---------------------------------------------------------------------------
extern "C" void kernel_launch(void* const* d_in, const int* in_sizes, int n_in,
                              void* d_out, int out_size, void* d_ws, size_t ws_size,
                              hipStream_t stream) {
  const int*   eids = (const int*)d_in[0];      // [B*N]
  const int*   adjE = (const int*)d_in[1];      // [V*K]
  const int*   adjR = (const int*)d_in[2];      // [V*K]
  const float* EE   = (const float*)d_in[3];    // [V*D]
  const float* RE   = (const float*)d_in[4];    // [R*D]
  const float* Watt = (const float*)d_in[5];    // [3*D]
  const float* batt = (const float*)d_in[6];    // [1]
  const float* Wc   = (const float*)d_in[7];    // [2*D*D]
  const float* bc   = (const float*)d_in[8];    // [D]
  float* out = (float*)d_out;

  float* att = (float*)d_ws;                    // N*K*B floats (512 KB)
  float* s0  = att + (size_t)N * K * B;         // V floats
  float* s1  = s0 + V;                          // V floats
  float* s2  = s1 + V;                          // R floats

  k_scores<<<(V + R + 3) / 4, 256, 0, stream>>>(EE, RE, Watt, s0, s1, s2);
  k_att<<<N * K, B, 0, stream>>>(eids, adjE, adjR, s0, s1, s2, batt, att);
  k_out<<<(B * N) / G, 256, 0, stream>>>(eids, adjE, EE, att, Wc, bc, out);
}

// Round 2
// 202.764 us; speedup vs baseline: 1.0812x; 1.0812x over previous
//
#include <hip/hip_runtime.h>

#define V 200000
#define R 100
#define D 128
#define K 20
#define B 128
#define N 50

// ---------------------------------------------------------------------------
// Kernel 1 (fused rel-score + logits):
//   att[(n*K+k)*B + b] = relu(ee.W0 + ne.W1 + nr.W2 + b_att)
// 256 threads = 4 waves; each wave owns one (b,n) pair.
// 4 groups of 16 lanes per wave; each group handles one neighbor row per
// iteration (5 iterations cover K=20) -> all 20 row-gathers in flight.
// ---------------------------------------------------------------------------
__global__ void k_logits(const int* __restrict__ eids,
                         const int* __restrict__ adjE,
                         const int* __restrict__ adjR,
                         const float* __restrict__ EE,
                         const float* __restrict__ RE,
                         const float* __restrict__ Watt,
                         const float* __restrict__ batt,
                         float* __restrict__ att) {
  const int lane = threadIdx.x & 63;
  const int wv   = threadIdx.x >> 6;
  const int bn   = blockIdx.x * 4 + wv;     // 0 .. B*N-1
  const int b = bn / N;
  const int n = bn % N;
  const int eid = eids[bn];

  // --- ee . W0 (full wave, float2/lane) ---
  const float2 wa_e = ((const float2*)Watt)[lane];
  const float2 e2   = ((const float2*)(EE + (size_t)eid * D))[lane];
  float p = e2.x * wa_e.x + e2.y * wa_e.y;
  #pragma unroll
  for (int off = 32; off > 0; off >>= 1) p += __shfl_down(p, off);
  const float s_ee = __shfl(p, 0) + batt[0];

  // --- neighbor dots: 16-lane groups ---
  const int g  = lane >> 4;                 // 0..3
  const int sl = lane & 15;                 // 0..15, covers dims 8*sl..8*sl+7
  const float4* wnp = (const float4*)(Watt + D + 8 * sl);
  const float4* wrp = (const float4*)(Watt + 2 * D + 8 * sl);
  const float4 wn0 = wnp[0], wn1 = wnp[1];
  const float4 wr0 = wrp[0], wr1 = wrp[1];

  const int* ae = adjE + eid * K;
  const int* ar = adjR + eid * K;

  float q[5];
  #pragma unroll
  for (int k5 = 0; k5 < 5; ++k5) {
    const int k = k5 * 4 + g;
    const int nid = ae[k];
    const int rid = ar[k];
    const float4* np = (const float4*)(EE + (size_t)nid * D + 8 * sl);
    const float4* rp = (const float4*)(RE + (size_t)rid * D + 8 * sl);
    const float4 n0 = np[0], n1 = np[1];
    const float4 r0 = rp[0], r1 = rp[1];
    float s = n0.x * wn0.x + n0.y * wn0.y + n0.z * wn0.z + n0.w * wn0.w
            + n1.x * wn1.x + n1.y * wn1.y + n1.z * wn1.z + n1.w * wn1.w
            + r0.x * wr0.x + r0.y * wr0.y + r0.z * wr0.z + r0.w * wr0.w
            + r1.x * wr1.x + r1.y * wr1.y + r1.z * wr1.z + r1.w * wr1.w;
    #pragma unroll
    for (int off = 8; off > 0; off >>= 1) s += __shfl_down(s, off, 16);
    q[k5] = s;
  }

  if (sl == 0) {
    #pragma unroll
    for (int k5 = 0; k5 < 5; ++k5) {
      const int k = k5 * 4 + g;
      const float logit = s_ee + q[k5];
      att[(n * K + k) * B + b] = logit > 0.0f ? logit : 0.0f;
    }
  }
}

// ---------------------------------------------------------------------------
// Kernel 2: softmax over the batch axis. One block of 128 threads per (n,k).
// ---------------------------------------------------------------------------
__global__ void k_softmax(float* __restrict__ att) {
  __shared__ float red[4];
  const int gg = blockIdx.x;           // 0 .. N*K-1
  const int t = threadIdx.x;           // 0 .. 127  (= b)
  const float x = att[gg * B + t];

  float m = x;
  #pragma unroll
  for (int off = 32; off > 0; off >>= 1) m = fmaxf(m, __shfl_down(m, off));
  if ((t & 63) == 0) red[t >> 6] = m;
  __syncthreads();
  const float mm = fmaxf(red[0], red[1]);

  const float e = __expf(x - mm);
  float s = e;
  #pragma unroll
  for (int off = 32; off > 0; off >>= 1) s += __shfl_down(s, off);
  if ((t & 63) == 0) red[2 + (t >> 6)] = s;
  __syncthreads();
  const float ss = red[2] + red[3];

  att[gg * B + t] = e / ss;
}

// ---------------------------------------------------------------------------
// Kernel 3: neighbor_att + epilogue GEMV.
// G=8 pairs per block, 256 threads.
// Phase 1 (gather) unchanged from the 206us version.
// Phase 2 register-blocked over a d-PAIR: each thread owns 2 output dims
// (float2 of Wc), so each agg[j] ds_read_b128 broadcast feeds 8 FMAs
// instead of 4 -> halves DS-pipe issue pressure. i-space split 4 ways (h4),
// partials combined in a final 4-way LDS reduction.
// ---------------------------------------------------------------------------
#define G 8
__global__ void k_out(const int* __restrict__ eids,
                      const int* __restrict__ adjE,
                      const float* __restrict__ EE,
                      const float* __restrict__ att,
                      const float* __restrict__ Wc,
                      const float* __restrict__ bc,
                      float* __restrict__ out) {
  __shared__ float agg[G][2 * D];        // 8 KB
  __shared__ float part[4][G][D];        // 16 KB
  __shared__ float s_att[G][K];
  __shared__ int   s_nid[G][K];

  const int t = threadIdx.x;             // 0 .. 255
  const int d = t & 127;
  const int h = t >> 7;
  const int base = blockIdx.x * G;

  // stage neighbor ids + attention scalars (160 threads)
  if (t < G * K) {
    const int j = t / K, k = t % K;
    const int bn = base + j;
    const int b = bn / N;
    const int n = bn % N;
    const int eid = eids[bn];
    s_nid[j][k] = adjE[eid * K + k];
    s_att[j][k] = att[(n * K + k) * B + b];
  }
  __syncthreads();

  // phase 1: gather + weighted sum; half h covers pairs j = h, h+2, ...
  #pragma unroll
  for (int jj = 0; jj < G / 2; ++jj) {
    const int j = h + jj * 2;
    const int bn = base + j;
    const int eid = eids[bn];
    const float ee = EE[(size_t)eid * D + d];
    float na = 0.0f;
    #pragma unroll
    for (int k = 0; k < K; ++k)
      na += s_att[j][k] * EE[(size_t)s_nid[j][k] * D + d];
    agg[j][d] = ee;
    agg[j][D + d] = na;
  }
  __syncthreads();

  // phase 2: thread t -> d2 = t&63 (owns dims 2*d2, 2*d2+1), h4 = t>>6.
  // i-range [64*h4, 64*h4+64). Wave h4's lanes share i -> agg reads are
  // uniform-address b128 broadcasts, each feeding 8 FMAs.
  {
    const int d2 = t & 63;
    const int h4 = t >> 6;
    float accx[G], accy[G];
    #pragma unroll
    for (int j = 0; j < G; ++j) { accx[j] = 0.0f; accy[j] = 0.0f; }
    const int ibase = h4 * 64;
    for (int c = 0; c < 16; ++c) {
      const int i = ibase + c * 4;
      const float2 w0 = *(const float2*)&Wc[(i + 0) * D + 2 * d2];
      const float2 w1 = *(const float2*)&Wc[(i + 1) * D + 2 * d2];
      const float2 w2 = *(const float2*)&Wc[(i + 2) * D + 2 * d2];
      const float2 w3 = *(const float2*)&Wc[(i + 3) * D + 2 * d2];
      #pragma unroll
      for (int j = 0; j < G; ++j) {
        const float4 a = *(const float4*)&agg[j][i];   // broadcast
        accx[j] += a.x * w0.x + a.y * w1.x + a.z * w2.x + a.w * w3.x;
        accy[j] += a.x * w0.y + a.y * w1.y + a.z * w2.y + a.w * w3.y;
      }
    }
    #pragma unroll
    for (int j = 0; j < G; ++j)
      *(float2*)&part[h4][j][2 * d2] = make_float2(accx[j], accy[j]);
  }
  __syncthreads();

  // combine 4 partials + bias + relu; thread t covers j = h*4 + jj, dim d
  const float bb = bc[d];
  #pragma unroll
  for (int jj = 0; jj < 4; ++jj) {
    const int j = h * 4 + jj;
    const float v = part[0][j][d] + part[1][j][d] + part[2][j][d]
                  + part[3][j][d] + bb;
    out[(size_t)(base + j) * D + d] = v > 0.0f ? v : 0.0f;
  }
}

// ---------------------------------------------------------------------------
extern "C" void kernel_launch(void* const* d_in, const int* in_sizes, int n_in,
                              void* d_out, int out_size, void* d_ws, size_t ws_size,
                              hipStream_t stream) {
  const int*   eids = (const int*)d_in[0];      // [B*N]
  const int*   adjE = (const int*)d_in[1];      // [V*K]
  const int*   adjR = (const int*)d_in[2];      // [V*K]
  const float* EE   = (const float*)d_in[3];    // [V*D]
  const float* RE   = (const float*)d_in[4];    // [R*D]
  const float* Watt = (const float*)d_in[5];    // [3*D]
  const float* batt = (const float*)d_in[6];    // [1]
  const float* Wc   = (const float*)d_in[7];    // [2*D*D]
  const float* bc   = (const float*)d_in[8];    // [D]
  float* out = (float*)d_out;

  float* att = (float*)d_ws;                    // N*K*B floats (512 KB)

  k_logits<<<(B * N) / 4, 256, 0, stream>>>(eids, adjE, adjR, EE, RE, Watt,
                                            batt, att);
  k_softmax<<<N * K, 128, 0, stream>>>(att);
  k_out<<<(B * N) / G, 256, 0, stream>>>(eids, adjE, EE, att, Wc, bc, out);
}